// Round 1
// baseline (732.797 us; speedup 1.0000x reference)
//
#include <hip/hip_runtime.h>

// PastFutureContext: B=8, N=1024, d=h=512
// Stages:
//  K0: prefix/suffix mask scans -> per-row scales
//  K1: proj = F @ W1^T + b1                         [8192,512]
//  K2: weight[b] = proj[b] @ F[b]^T                 [1024,1024] x8 (chunked in ws)
//  K3: past/fut[b,i,:] = scale * sum_j masked(w)*sm_j*F[b,j,:]
//  K4: out = past@W2a^T + F@W2b^T + fut@W2c^T + b2  [8192,512]
// All GEMMs: 64x64 tile, BK=16, 256 thr, 4x4 microtile, K-major LDS (float4 reads).

constexpr int BATCH = 8;
constexpr int SEQ   = 1024;
constexpr int DIM   = 512;
constexpr int HID   = 512;

using f4 = __attribute__((ext_vector_type(4))) float;

__device__ __forceinline__ void mm_tile(const float (*As)[68], const float (*Bs)[68],
                                        int ty, int tx, float acc[4][4]) {
#pragma unroll
  for (int kk = 0; kk < 16; ++kk) {
    f4 a = *(const f4*)&As[kk][ty * 4];
    f4 b = *(const f4*)&Bs[kk][tx * 4];
#pragma unroll
    for (int i = 0; i < 4; ++i)
#pragma unroll
      for (int j = 0; j < 4; ++j)
        acc[i][j] = fmaf(a[i], b[j], acc[i][j]);
  }
}

#define TILE_DECL                      \
  const int tid = threadIdx.x;         \
  const int tx = tid & 15;             \
  const int ty = tid >> 4;             \
  const int lr = tid >> 2;             \
  const int lc = tid & 3;

// ---- K0: scales ------------------------------------------------------------
__global__ void scales_kernel(const int* __restrict__ smask,
                              float* __restrict__ sp, float* __restrict__ sf) {
  const int b = threadIdx.x;
  if (b >= BATCH) return;
  const int* s = smask + b * SEQ;
  float c = 0.f;
  for (int i = 0; i < SEQ; ++i) {           // P_i = sum_{j<i} sm_j
    sp[b * SEQ + i] = s[i] ? 1.f / (c + 1e-8f) : 0.f;
    c += (float)s[i];
  }
  c = 0.f;
  for (int i = SEQ - 1; i >= 0; --i) {      // F_i = sum_{j>i} sm_j
    sf[b * SEQ + i] = s[i] ? 1.f / (c + 1e-8f) : 0.f;
    c += (float)s[i];
  }
}

// ---- K1: proj = F @ W1^T + b1 ----------------------------------------------
__global__ __launch_bounds__(256) void proj_kernel(
    const float* __restrict__ F, const float* __restrict__ W1,
    const float* __restrict__ b1, float* __restrict__ proj) {
  __shared__ float As[16][68];
  __shared__ float Bs[16][68];
  TILE_DECL
  const int m0 = blockIdx.y * 64;
  const int n0 = blockIdx.x * 64;
  float acc[4][4] = {};
  for (int k0 = 0; k0 < DIM; k0 += 16) {
    f4 av = *(const f4*)&F[(size_t)(m0 + lr) * DIM + k0 + lc * 4];
    f4 bv = *(const f4*)&W1[(size_t)(n0 + lr) * DIM + k0 + lc * 4];
    __syncthreads();
#pragma unroll
    for (int e = 0; e < 4; ++e) { As[lc * 4 + e][lr] = av[e]; Bs[lc * 4 + e][lr] = bv[e]; }
    __syncthreads();
    mm_tile(As, Bs, ty, tx, acc);
  }
#pragma unroll
  for (int i = 0; i < 4; ++i) {
    const int m = m0 + ty * 4 + i;
    float* dst = &proj[(size_t)m * HID + n0 + tx * 4];
#pragma unroll
    for (int j = 0; j < 4; ++j) dst[j] = acc[i][j] + b1[n0 + tx * 4 + j];
  }
}

// ---- K2: weight[b] = proj[b] @ F[b]^T ---------------------------------------
__global__ __launch_bounds__(256) void weight_kernel(
    const float* __restrict__ proj, const float* __restrict__ F,
    float* __restrict__ Wt, int b0) {
  __shared__ float As[16][68];
  __shared__ float Bs[16][68];
  TILE_DECL
  const int b = b0 + blockIdx.z;
  const float* A  = proj + (size_t)b * SEQ * DIM;
  const float* Bm = F    + (size_t)b * SEQ * DIM;
  float* C = Wt + (size_t)blockIdx.z * SEQ * SEQ;
  const int m0 = blockIdx.y * 64;
  const int n0 = blockIdx.x * 64;
  float acc[4][4] = {};
  for (int k0 = 0; k0 < DIM; k0 += 16) {
    f4 av = *(const f4*)&A[(size_t)(m0 + lr) * DIM + k0 + lc * 4];
    f4 bv = *(const f4*)&Bm[(size_t)(n0 + lr) * DIM + k0 + lc * 4];
    __syncthreads();
#pragma unroll
    for (int e = 0; e < 4; ++e) { As[lc * 4 + e][lr] = av[e]; Bs[lc * 4 + e][lr] = bv[e]; }
    __syncthreads();
    mm_tile(As, Bs, ty, tx, acc);
  }
#pragma unroll
  for (int i = 0; i < 4; ++i) {
    float* dst = &C[(size_t)(m0 + ty * 4 + i) * SEQ + n0 + tx * 4];
#pragma unroll
    for (int j = 0; j < 4; ++j) dst[j] = acc[i][j];
  }
}

// ---- K3: masked triangular sums -> past/fut features ------------------------
__global__ __launch_bounds__(256) void pf_kernel(
    const float* __restrict__ Wt, const float* __restrict__ F,
    const int* __restrict__ smask,
    const float* __restrict__ scaleP, const float* __restrict__ scaleF,
    float* __restrict__ pastf, float* __restrict__ futf, int b0) {
  __shared__ float AsP[16][68];
  __shared__ float AsF[16][68];
  __shared__ float Bs[16][68];
  TILE_DECL
  const int b = b0 + blockIdx.z;
  const float* A  = Wt + (size_t)blockIdx.z * SEQ * SEQ;  // weight[b], ws-local
  const float* Bm = F  + (size_t)b * SEQ * DIM;
  const int* sm = smask + b * SEQ;
  const int i0 = blockIdx.y * 64;
  const int n0 = blockIdx.x * 64;
  const int brow = tid >> 4;        // Bs is [k=j][n=d]: direct (no transpose)
  const int bcol = (tid & 15) * 4;
  float accp[4][4] = {};
  float accf[4][4] = {};
  for (int j0 = 0; j0 < SEQ; j0 += 16) {
    f4 av = *(const f4*)&A[(size_t)(i0 + lr) * SEQ + j0 + lc * 4];
    f4 bv = *(const f4*)&Bm[(size_t)(j0 + brow) * DIM + n0 + bcol];
    const int gi = i0 + lr;
    __syncthreads();
#pragma unroll
    for (int e = 0; e < 4; ++e) {
      const int gj = j0 + lc * 4 + e;
      const float v = av[e] * (float)sm[gj];
      AsP[lc * 4 + e][lr] = (gj < gi) ? v : 0.f;
      AsF[lc * 4 + e][lr] = (gj > gi) ? v : 0.f;
    }
    *(f4*)&Bs[brow][bcol] = bv;
    __syncthreads();
    if (j0 < i0 + 64) mm_tile(AsP, Bs, ty, tx, accp);   // tile has any j<i
    if (j0 + 15 > i0) mm_tile(AsF, Bs, ty, tx, accf);   // tile has any j>i
  }
#pragma unroll
  for (int i = 0; i < 4; ++i) {
    const int gi = i0 + ty * 4 + i;
    const float spv = scaleP[b * SEQ + gi];
    const float sfv = scaleF[b * SEQ + gi];
    float* dp = &pastf[((size_t)b * SEQ + gi) * DIM + n0 + tx * 4];
    float* df = &futf [((size_t)b * SEQ + gi) * DIM + n0 + tx * 4];
#pragma unroll
    for (int j = 0; j < 4; ++j) { dp[j] = accp[i][j] * spv; df[j] = accf[i][j] * sfv; }
  }
}

// ---- K4: out = past@W2a^T + F@W2b^T + fut@W2c^T + b2 -------------------------
__global__ __launch_bounds__(256) void out_kernel(
    const float* __restrict__ pastf, const float* __restrict__ F,
    const float* __restrict__ futf,
    const float* __restrict__ W2, const float* __restrict__ b2,
    float* __restrict__ out) {
  __shared__ float As[16][68];
  __shared__ float Bs[16][68];
  TILE_DECL
  const int m0 = blockIdx.y * 64;
  const int n0 = blockIdx.x * 64;
  float acc[4][4] = {};
  for (int seg = 0; seg < 3; ++seg) {
    const float* A = (seg == 0) ? pastf : (seg == 1) ? F : futf;
    for (int k0 = 0; k0 < DIM; k0 += 16) {
      f4 av = *(const f4*)&A[(size_t)(m0 + lr) * DIM + k0 + lc * 4];
      f4 bv = *(const f4*)&W2[(size_t)(n0 + lr) * (3 * HID) + seg * DIM + k0 + lc * 4];
      __syncthreads();
#pragma unroll
      for (int e = 0; e < 4; ++e) { As[lc * 4 + e][lr] = av[e]; Bs[lc * 4 + e][lr] = bv[e]; }
      __syncthreads();
      mm_tile(As, Bs, ty, tx, acc);
    }
  }
#pragma unroll
  for (int i = 0; i < 4; ++i) {
    float* dst = &out[(size_t)(m0 + ty * 4 + i) * HID + n0 + tx * 4];
#pragma unroll
    for (int j = 0; j < 4; ++j) dst[j] = acc[i][j] + b2[n0 + tx * 4 + j];
  }
}

extern "C" void kernel_launch(void* const* d_in, const int* in_sizes, int n_in,
                              void* d_out, int out_size, void* d_ws, size_t ws_size,
                              hipStream_t stream) {
  const float* F  = (const float*)d_in[0];
  const int*   sm = (const int*)  d_in[1];
  const float* W1 = (const float*)d_in[2];
  const float* b1 = (const float*)d_in[3];
  const float* W2 = (const float*)d_in[4];
  const float* b2 = (const float*)d_in[5];
  float* out = (float*)d_out;

  char* ws = (char*)d_ws;
  size_t off = 0;
  auto take = [&](size_t bytes) -> float* {
    float* p = (float*)(ws + off);
    off += (bytes + 255) & ~(size_t)255;
    return p;
  };
  float* proj   = take((size_t)BATCH * SEQ * DIM * 4);
  float* pastf  = take((size_t)BATCH * SEQ * DIM * 4);
  float* futf   = take((size_t)BATCH * SEQ * DIM * 4);
  float* scaleP = take((size_t)BATCH * SEQ * 4);
  float* scaleF = take((size_t)BATCH * SEQ * 4);

  // weight chunk: as many batches of [SEQ,SEQ] f32 as fit in remaining ws
  const size_t wbytes = (size_t)SEQ * SEQ * 4;
  int chunk = (ws_size > off) ? (int)((ws_size - off) / wbytes) : 1;
  if (chunk > BATCH) chunk = BATCH;
  if (chunk < 1) chunk = 1;
  float* wbuf = (float*)(ws + off);

  scales_kernel<<<dim3(1), dim3(64), 0, stream>>>(sm, scaleP, scaleF);
  proj_kernel<<<dim3(HID / 64, (BATCH * SEQ) / 64), dim3(256), 0, stream>>>(F, W1, b1, proj);
  for (int b0 = 0; b0 < BATCH; b0 += chunk) {
    const int nb = (BATCH - b0 < chunk) ? (BATCH - b0) : chunk;
    weight_kernel<<<dim3(SEQ / 64, SEQ / 64, nb), dim3(256), 0, stream>>>(proj, F, wbuf, b0);
    pf_kernel<<<dim3(DIM / 64, SEQ / 64, nb), dim3(256), 0, stream>>>(
        wbuf, F, sm, scaleP, scaleF, pastf, futf, b0);
  }
  out_kernel<<<dim3(HID / 64, (BATCH * SEQ) / 64), dim3(256), 0, stream>>>(
      pastf, F, futf, W2, b2, out);
}

// Round 2
// 183.691 us; speedup vs baseline: 3.9893x; 3.9893x over previous
//
#include <hip/hip_runtime.h>

// PastFutureContext: B=8, N=1024, d=h=512 — bf16 MFMA path.
// Stages:
//  S0: parallel mask scans -> per-row scales (1/(P_i+eps), 1/(F_i+eps))
//  S1: cvt F,W1,W2 -> bf16; Ftr[b,d,j] = bf16(F[b,j,d]*sm_j)  (LDS-tiled transpose)
//  S2: proj = F @ W1^T + b1            (bf16 out)
//  S3: weight[b] = proj[b] @ F[b]^T    (bf16 out, ws-chunked)
//  S4: past/fut[b,i,:] = scale_i * sum_j tri(w)*[sm_j*F[b,j,:]]  (triangular-masked MFMA)
//  S5: out = past@W2a^T + F@W2b^T + fut@W2c^T + b2   (f32 out)
// All GEMMs: A[m][k] row-major, Bt[n][k] row-major, D = A @ Bt^T.
// Fragments read DIRECTLY from global (all contiguous 16B/lane), no LDS.

constexpr int BATCH = 8;
constexpr int SEQ   = 1024;
constexpr int DIM   = 512;
constexpr int HID   = 512;

typedef __bf16 bf16_t;
typedef bf16_t bf16x8 __attribute__((ext_vector_type(8)));
typedef float  f32x4  __attribute__((ext_vector_type(4)));
typedef float  f4     __attribute__((ext_vector_type(4)));

// ---- S0: parallel scales ----------------------------------------------------
__global__ __launch_bounds__(1024) void scales_kernel(
    const int* __restrict__ smask, float* __restrict__ sp, float* __restrict__ sf) {
  const int b = blockIdx.x, t = threadIdx.x;
  const int v = smask[b * SEQ + t];
  int x = v;
#pragma unroll
  for (int o = 1; o < 64; o <<= 1) {            // wave inclusive scan
    int y = __shfl_up(x, o, 64);
    if ((t & 63) >= o) x += y;
  }
  __shared__ int wsum[16], wpre[17];
  if ((t & 63) == 63) wsum[t >> 6] = x;
  __syncthreads();
  if (t == 0) { int c = 0; for (int w = 0; w < 16; ++w) { wpre[w] = c; c += wsum[w]; } wpre[16] = c; }
  __syncthreads();
  const int inc = x + wpre[t >> 6];
  const float P  = (float)(inc - v);            // sum_{j<i} sm_j
  const float Fu = (float)(wpre[16] - inc);     // sum_{j>i} sm_j
  sp[b * SEQ + t] = v ? 1.f / (P  + 1e-8f) : 0.f;
  sf[b * SEQ + t] = v ? 1.f / (Fu + 1e-8f) : 0.f;
}

// ---- S1a: generic f32 -> bf16 (x8 per thread) -------------------------------
__global__ void cvt_kernel(const float* __restrict__ in, bf16_t* __restrict__ out, int n8) {
  const int i = blockIdx.x * blockDim.x + threadIdx.x;
  if (i >= n8) return;
  const f4* p = (const f4*)(in + (size_t)i * 8);
  f4 v0 = p[0], v1 = p[1];
  bf16x8 o;
  o[0] = (bf16_t)v0[0]; o[1] = (bf16_t)v0[1]; o[2] = (bf16_t)v0[2]; o[3] = (bf16_t)v0[3];
  o[4] = (bf16_t)v1[0]; o[5] = (bf16_t)v1[1]; o[6] = (bf16_t)v1[2]; o[7] = (bf16_t)v1[3];
  *(bf16x8*)(out + (size_t)i * 8) = o;
}

// ---- S1b: Ftr[b,d,j] = bf16(F[b,j,d] * sm_j) --------------------------------
__global__ __launch_bounds__(256) void trmask_kernel(
    const float* __restrict__ F, const int* __restrict__ smask, bf16_t* __restrict__ Ftr) {
  __shared__ float tile[64][65];
  const int b = blockIdx.z;
  const int d0 = blockIdx.x * 64, j0 = blockIdx.y * 64;
  const int t = threadIdx.x;
  const int jr = t >> 2, dc = (t & 3) * 16;
  const float* src = F + ((size_t)b * SEQ + j0 + jr) * DIM + d0 + dc;
#pragma unroll
  for (int c = 0; c < 16; c += 4) {
    f4 v = *(const f4*)&src[c];
    tile[jr][dc + c] = v[0]; tile[jr][dc + c + 1] = v[1];
    tile[jr][dc + c + 2] = v[2]; tile[jr][dc + c + 3] = v[3];
  }
  __syncthreads();
  const int dr = t >> 2, jc = (t & 3) * 16;
  bf16_t* dst = Ftr + ((size_t)b * DIM + d0 + dr) * SEQ + j0 + jc;
#pragma unroll
  for (int e = 0; e < 16; ++e)
    dst[e] = (bf16_t)(tile[jc + e][dr] * (float)smask[b * SEQ + j0 + jc + e]);
}

// ---- generic wave GEMM core: acc += A[m0..m0+63][k] @ Bt[n0..n0+63][k]^T ----
template <int KTOT>
__device__ __forceinline__ void mfma_block(
    const bf16_t* __restrict__ A, int lda, const bf16_t* __restrict__ Bt, int ldb,
    f32x4 acc[4][4], int m0, int n0) {
  const int lane = threadIdx.x & 63;
  const int fr = lane & 15;
  const int fk = (lane >> 4) << 3;
  for (int k0 = 0; k0 < KTOT; k0 += 32) {
    bf16x8 a[4], b[4];
#pragma unroll
    for (int s = 0; s < 4; ++s)
      a[s] = *(const bf16x8*)&A[(size_t)(m0 + s * 16 + fr) * lda + k0 + fk];
#pragma unroll
    for (int t = 0; t < 4; ++t)
      b[t] = *(const bf16x8*)&Bt[(size_t)(n0 + t * 16 + fr) * ldb + k0 + fk];
#pragma unroll
    for (int s = 0; s < 4; ++s)
#pragma unroll
      for (int t = 0; t < 4; ++t)
        acc[s][t] = __builtin_amdgcn_mfma_f32_16x16x32_bf16(a[s], b[t], acc[s][t], 0, 0, 0);
  }
}

#define WAVE_TILE                                   \
  const int w  = threadIdx.x >> 6;                  \
  const int m0 = blockIdx.y * 128 + (w >> 1) * 64;  \
  const int n0 = blockIdx.x * 128 + (w & 1) * 64;   \
  const int lane = threadIdx.x & 63;                \
  const int cr = (lane >> 4) * 4, cc = lane & 15;

// ---- S2: proj = F @ W1^T + b1 (bf16 out) ------------------------------------
__global__ __launch_bounds__(256) void proj_mfma(
    const bf16_t* __restrict__ Fbf, const bf16_t* __restrict__ W1bf,
    const float* __restrict__ b1, bf16_t* __restrict__ projbf) {
  WAVE_TILE
  f32x4 acc[4][4] = {};
  mfma_block<DIM>(Fbf, DIM, W1bf, DIM, acc, m0, n0);
#pragma unroll
  for (int s = 0; s < 4; ++s)
#pragma unroll
    for (int t = 0; t < 4; ++t) {
      const int col = n0 + t * 16 + cc;
      const float bias = b1[col];
#pragma unroll
      for (int r = 0; r < 4; ++r)
        projbf[(size_t)(m0 + s * 16 + cr + r) * HID + col] = (bf16_t)(acc[s][t][r] + bias);
    }
}

// ---- S3: weight[b] = proj[b] @ F[b]^T (bf16 out) ----------------------------
__global__ __launch_bounds__(256) void weight_mfma(
    const bf16_t* __restrict__ projbf, const bf16_t* __restrict__ Fbf,
    bf16_t* __restrict__ wbuf, int b0) {
  WAVE_TILE
  const int b = b0 + blockIdx.z;
  const bf16_t* A  = projbf + (size_t)b * SEQ * DIM;
  const bf16_t* Bt = Fbf    + (size_t)b * SEQ * DIM;
  bf16_t* C = wbuf + (size_t)blockIdx.z * SEQ * SEQ;
  f32x4 acc[4][4] = {};
  mfma_block<DIM>(A, DIM, Bt, DIM, acc, m0, n0);
#pragma unroll
  for (int s = 0; s < 4; ++s)
#pragma unroll
    for (int t = 0; t < 4; ++t)
#pragma unroll
      for (int r = 0; r < 4; ++r)
        C[(size_t)(m0 + s * 16 + cr + r) * SEQ + n0 + t * 16 + cc] = (bf16_t)acc[s][t][r];
}

// ---- S4: triangular-masked sums -> past/fut (bf16 out, scaled) --------------
__global__ __launch_bounds__(256) void pf_mfma(
    const bf16_t* __restrict__ wbuf, const bf16_t* __restrict__ Ftr,
    const float* __restrict__ scaleP, const float* __restrict__ scaleF,
    bf16_t* __restrict__ pastbf, bf16_t* __restrict__ futbf, int b0) {
  WAVE_TILE
  const int b = b0 + blockIdx.z;
  const bf16_t* A  = wbuf + (size_t)blockIdx.z * SEQ * SEQ;   // [i][j]
  const bf16_t* Bt = Ftr  + (size_t)b * DIM * SEQ;            // [d][j]
  const int fr = lane & 15;
  const int fk = (lane >> 4) << 3;
  f32x4 accP[4][4] = {}, accF[4][4] = {};
  for (int k0 = 0; k0 < SEQ; k0 += 32) {
    bf16x8 bfr[4];
#pragma unroll
    for (int t = 0; t < 4; ++t)
      bfr[t] = *(const bf16x8*)&Bt[(size_t)(n0 + t * 16 + fr) * SEQ + k0 + fk];
#pragma unroll
    for (int s = 0; s < 4; ++s) {
      const int rlo = m0 + s * 16, rhi = rlo + 15;   // frag i-range (wave-uniform)
      const bool pFull = (k0 + 31 < rlo),  pAny = (k0 < rhi);
      const bool fFull = (k0 > rhi),       fAny = (k0 + 31 > rlo);
      if (!pAny && !fFull && !fAny) continue;
      const int i  = rlo + fr;                        // per-lane row
      const int jb = k0 + fk;                         // per-lane j base
      bf16x8 av;
      if (pAny || fAny || fFull)
        av = *(const bf16x8*)&A[(size_t)i * SEQ + jb];
      if (pFull) {
#pragma unroll
        for (int t = 0; t < 4; ++t)
          accP[s][t] = __builtin_amdgcn_mfma_f32_16x16x32_bf16(av, bfr[t], accP[s][t], 0, 0, 0);
      } else if (pAny) {
        bf16x8 ap = av;
        const int cut = i - jb;                       // keep e < cut  (j < i)
#pragma unroll
        for (int e = 0; e < 8; ++e) if (e >= cut) ap[e] = (bf16_t)0.f;
#pragma unroll
        for (int t = 0; t < 4; ++t)
          accP[s][t] = __builtin_amdgcn_mfma_f32_16x16x32_bf16(ap, bfr[t], accP[s][t], 0, 0, 0);
      }
      if (fFull) {
#pragma unroll
        for (int t = 0; t < 4; ++t)
          accF[s][t] = __builtin_amdgcn_mfma_f32_16x16x32_bf16(av, bfr[t], accF[s][t], 0, 0, 0);
      } else if (fAny) {
        bf16x8 af = av;
        const int cut = i - jb;                       // zero e <= cut (keep j > i)
#pragma unroll
        for (int e = 0; e < 8; ++e) if (e <= cut) af[e] = (bf16_t)0.f;
#pragma unroll
        for (int t = 0; t < 4; ++t)
          accF[s][t] = __builtin_amdgcn_mfma_f32_16x16x32_bf16(af, bfr[t], accF[s][t], 0, 0, 0);
      }
    }
  }
#pragma unroll
  for (int s = 0; s < 4; ++s)
#pragma unroll
    for (int t = 0; t < 4; ++t)
#pragma unroll
      for (int r = 0; r < 4; ++r) {
        const int row = m0 + s * 16 + cr + r;
        const int col = n0 + t * 16 + cc;
        const float spv = scaleP[b * SEQ + row];
        const float sfv = scaleF[b * SEQ + row];
        pastbf[((size_t)b * SEQ + row) * DIM + col] = (bf16_t)(accP[s][t][r] * spv);
        futbf [((size_t)b * SEQ + row) * DIM + col] = (bf16_t)(accF[s][t][r] * sfv);
      }
}

// ---- S5: out = past@W2a^T + F@W2b^T + fut@W2c^T + b2 (f32 out) --------------
__global__ __launch_bounds__(256) void out_mfma(
    const bf16_t* __restrict__ pastbf, const bf16_t* __restrict__ Fbf,
    const bf16_t* __restrict__ futbf,  const bf16_t* __restrict__ W2bf,
    const float* __restrict__ b2, float* __restrict__ out) {
  WAVE_TILE
  f32x4 acc[4][4] = {};
  mfma_block<DIM>(pastbf, DIM, W2bf,            3 * HID, acc, m0, n0);
  mfma_block<DIM>(Fbf,    DIM, W2bf + HID,      3 * HID, acc, m0, n0);
  mfma_block<DIM>(futbf,  DIM, W2bf + 2 * HID,  3 * HID, acc, m0, n0);
#pragma unroll
  for (int s = 0; s < 4; ++s)
#pragma unroll
    for (int t = 0; t < 4; ++t) {
      const int col = n0 + t * 16 + cc;
      const float bias = b2[col];
#pragma unroll
      for (int r = 0; r < 4; ++r)
        out[(size_t)(m0 + s * 16 + cr + r) * HID + col] = acc[s][t][r] + bias;
    }
}

extern "C" void kernel_launch(void* const* d_in, const int* in_sizes, int n_in,
                              void* d_out, int out_size, void* d_ws, size_t ws_size,
                              hipStream_t stream) {
  const float* F  = (const float*)d_in[0];
  const int*   sm = (const int*)  d_in[1];
  const float* W1 = (const float*)d_in[2];
  const float* b1 = (const float*)d_in[3];
  const float* W2 = (const float*)d_in[4];
  const float* b2 = (const float*)d_in[5];
  float* out = (float*)d_out;

  char* ws = (char*)d_ws;
  size_t off = 0;
  auto take = [&](size_t bytes) -> void* {
    void* p = ws + off;
    off += (bytes + 255) & ~(size_t)255;
    return p;
  };
  bf16_t* Fbf    = (bf16_t*)take((size_t)BATCH * SEQ * DIM * 2);
  bf16_t* Ftr    = (bf16_t*)take((size_t)BATCH * DIM * SEQ * 2);
  bf16_t* projbf = (bf16_t*)take((size_t)BATCH * SEQ * HID * 2);
  bf16_t* pastbf = (bf16_t*)take((size_t)BATCH * SEQ * DIM * 2);
  bf16_t* futbf  = (bf16_t*)take((size_t)BATCH * SEQ * DIM * 2);
  bf16_t* W1bf   = (bf16_t*)take((size_t)HID * DIM * 2);
  bf16_t* W2bf   = (bf16_t*)take((size_t)HID * 3 * HID * 2);
  float*  scaleP = (float*) take((size_t)BATCH * SEQ * 4);
  float*  scaleF = (float*) take((size_t)BATCH * SEQ * 4);

  const size_t wbytes = (size_t)SEQ * SEQ * 2;       // bf16 weight per batch
  int chunk = (ws_size > off) ? (int)((ws_size - off) / wbytes) : 1;
  if (chunk > BATCH) chunk = BATCH;
  if (chunk < 1) chunk = 1;
  bf16_t* wbuf = (bf16_t*)(ws + off);

  scales_kernel<<<dim3(BATCH), dim3(1024), 0, stream>>>(sm, scaleP, scaleF);
  cvt_kernel<<<dim3((BATCH * SEQ * DIM / 8 + 255) / 256), dim3(256), 0, stream>>>(F, Fbf, BATCH * SEQ * DIM / 8);
  cvt_kernel<<<dim3((HID * DIM / 8 + 255) / 256), dim3(256), 0, stream>>>(W1, W1bf, HID * DIM / 8);
  cvt_kernel<<<dim3((HID * 3 * HID / 8 + 255) / 256), dim3(256), 0, stream>>>(W2, W2bf, HID * 3 * HID / 8);
  trmask_kernel<<<dim3(DIM / 64, SEQ / 64, BATCH), dim3(256), 0, stream>>>(F, sm, Ftr);

  proj_mfma<<<dim3(HID / 128, BATCH * SEQ / 128), dim3(256), 0, stream>>>(Fbf, W1bf, b1, projbf);
  for (int b0 = 0; b0 < BATCH; b0 += chunk) {
    const int nb = (BATCH - b0 < chunk) ? (BATCH - b0) : chunk;
    weight_mfma<<<dim3(SEQ / 128, SEQ / 128, nb), dim3(256), 0, stream>>>(projbf, Fbf, wbuf, b0);
    pf_mfma<<<dim3(DIM / 128, SEQ / 128, nb), dim3(256), 0, stream>>>(
        wbuf, Ftr, scaleP, scaleF, pastbf, futbf, b0);
  }
  out_mfma<<<dim3(HID / 128, BATCH * SEQ / 128), dim3(256), 0, stream>>>(
      pastbf, Fbf, futbf, W2bf, b2, out);
}

// Round 3
// 114.615 us; speedup vs baseline: 6.3935x; 1.6027x over previous
//
#include <hip/hip_runtime.h>

// PastFutureContext: B=8, N=1024, d=h=512 — bf16 MFMA, LDS-staged (m97 structure).
// Math: out = sp_i * (trilW @ GaT^T) + sf_i * (triuW @ GcT^T) + Gb, where
//   W[b]    = proj[b] @ F[b]^T        (proj = F@W1^T + b1)
//   GacT[b] = [W2a;W2c] @ F[b]^T * sm_j   (transposed-output so tri's B is K-contiguous)
//   Gb      = F @ W2b^T + b2          (fused into proj GEMM via stacked B)
// GEMM core: 128x128 tile (tri: 128x64), BK=32, 256 thr, global_load_lds dwordx4
// staging, 2-barrier loop, 4 waves x 64x64 (16x16x32 bf16 MFMA).

constexpr int BATCH = 8;
constexpr int SEQ   = 1024;
constexpr int DIM   = 512;
constexpr int HID   = 512;

typedef __bf16 bf16_t;
typedef bf16_t bf16x8 __attribute__((ext_vector_type(8)));
typedef float  f32x4  __attribute__((ext_vector_type(4)));
typedef float  f4     __attribute__((ext_vector_type(4)));

typedef __attribute__((address_space(1))) void gv_t;
typedef __attribute__((address_space(3))) void lv_t;

__device__ __forceinline__ void gload16(const bf16_t* g, bf16_t* l) {
  __builtin_amdgcn_global_load_lds((gv_t*)g, (lv_t*)l, 16, 0, 0);
}

// Stage a [ROWS x 32] bf16 tile (row-major, leading dim ld elems) into linear LDS.
// LDS dest is wave-uniform base; HW scatters lane l at +16B*l. Row r = seg*16 + l/4,
// col k = (l%4)*8  ->  linear elem idx = seg*512 + l*8.
template <int ROWS>
__device__ __forceinline__ void stage(const bf16_t* g, int ld, bf16_t* lds,
                                      int w, int lane) {
  const int r0 = lane >> 2;
  const int k  = (lane & 3) * 8;
#pragma unroll
  for (int i = 0; i < ROWS / 64; ++i) {
    const int s = w * (ROWS / 64) + i;
    gload16(g + (size_t)(s * 16 + r0) * ld + k, lds + s * 512);
  }
}

// ---- S0: parallel scales ----------------------------------------------------
__global__ __launch_bounds__(1024) void scales_kernel(
    const int* __restrict__ smask, float* __restrict__ sp, float* __restrict__ sf) {
  const int b = blockIdx.x, t = threadIdx.x;
  const int v = smask[b * SEQ + t];
  int x = v;
#pragma unroll
  for (int o = 1; o < 64; o <<= 1) {
    int y = __shfl_up(x, o, 64);
    if ((t & 63) >= o) x += y;
  }
  __shared__ int wsum[16], wpre[17];
  if ((t & 63) == 63) wsum[t >> 6] = x;
  __syncthreads();
  if (t == 0) { int c = 0; for (int w = 0; w < 16; ++w) { wpre[w] = c; c += wsum[w]; } wpre[16] = c; }
  __syncthreads();
  const int inc = x + wpre[t >> 6];
  const float P  = (float)(inc - v);
  const float Fu = (float)(wpre[16] - inc);
  sp[b * SEQ + t] = v ? 1.f / (P  + 1e-8f) : 0.f;
  sf[b * SEQ + t] = v ? 1.f / (Fu + 1e-8f) : 0.f;
}

// ---- S1a: F -> bf16 ----------------------------------------------------------
__global__ void cvt_kernel(const float* __restrict__ in, bf16_t* __restrict__ out, int n8) {
  const int i = blockIdx.x * blockDim.x + threadIdx.x;
  if (i >= n8) return;
  const f4* p = (const f4*)(in + (size_t)i * 8);
  f4 v0 = p[0], v1 = p[1];
  bf16x8 o;
  o[0] = (bf16_t)v0[0]; o[1] = (bf16_t)v0[1]; o[2] = (bf16_t)v0[2]; o[3] = (bf16_t)v0[3];
  o[4] = (bf16_t)v1[0]; o[5] = (bf16_t)v1[1]; o[6] = (bf16_t)v1[2]; o[7] = (bf16_t)v1[3];
  *(bf16x8*)(out + (size_t)i * 8) = o;
}

// ---- S1b: weights -> bf16, restacked ----------------------------------------
// Wpg [1024][512]: rows 0-511 = W1, rows 512-1023 = W2b (= W2[:,512:1024])
// W2ac[1024][512]: rows 0-511 = W2a (= W2[:,0:512]), rows 512-1023 = W2c (= W2[:,1024:1536])
__global__ __launch_bounds__(256) void prepw_kernel(
    const float* __restrict__ W1, const float* __restrict__ W2,
    bf16_t* __restrict__ Wpg, bf16_t* __restrict__ W2ac) {
  const int idx = blockIdx.x * 256 + threadIdx.x;   // 2048 rows x 64 thr/row
  const int r = idx >> 6, c8 = (idx & 63) * 8;
  const float* src;
  bf16_t* dst;
  if (r < 512)        { src = W1 + (size_t)r * 512 + c8;                    dst = Wpg  + (size_t)r * 512 + c8; }
  else if (r < 1024)  { src = W2 + (size_t)(r - 512) * 1536 + 512 + c8;     dst = Wpg  + (size_t)r * 512 + c8; }
  else if (r < 1536)  { src = W2 + (size_t)(r - 1024) * 1536 + c8;          dst = W2ac + (size_t)(r - 1024) * 512 + c8; }
  else                { src = W2 + (size_t)(r - 1536) * 1536 + 1024 + c8;   dst = W2ac + (size_t)(r - 1024) * 512 + c8; }
  f4 v0 = *(const f4*)src, v1 = *(const f4*)(src + 4);
  bf16x8 o;
  o[0] = (bf16_t)v0[0]; o[1] = (bf16_t)v0[1]; o[2] = (bf16_t)v0[2]; o[3] = (bf16_t)v0[3];
  o[4] = (bf16_t)v1[0]; o[5] = (bf16_t)v1[1]; o[6] = (bf16_t)v1[2]; o[7] = (bf16_t)v1[3];
  *(bf16x8*)dst = o;
}

// ---- shared 128x128 GEMM core (acc += A(128xK) @ Bt(128xK)^T tile) -----------
#define GEMM_CORE(Ab, lda, Btb, ldb, K, As, Bs, acc)                          \
  {                                                                           \
    for (int k0 = 0; k0 < (K); k0 += 32) {                                    \
      __syncthreads();                                                        \
      stage<128>((Ab) + k0, (lda), As, w, lane);                              \
      stage<128>((Btb) + k0, (ldb), Bs, w, lane);                             \
      __syncthreads();                                                        \
      bf16x8 a[4], b[4];                                                      \
      _Pragma("unroll")                                                       \
      for (int s = 0; s < 4; ++s) a[s] = *(const bf16x8*)&As[(mw + s * 16 + fr) * 32 + fk]; \
      _Pragma("unroll")                                                       \
      for (int t = 0; t < 4; ++t) b[t] = *(const bf16x8*)&Bs[(nw + t * 16 + fr) * 32 + fk]; \
      _Pragma("unroll")                                                       \
      for (int s = 0; s < 4; ++s)                                             \
        _Pragma("unroll")                                                     \
        for (int t = 0; t < 4; ++t)                                           \
          acc[s][t] = __builtin_amdgcn_mfma_f32_16x16x32_bf16(a[s], b[t], acc[s][t], 0, 0, 0); \
    }                                                                         \
  }

#define TILE_IDS                                  \
  const int tid = threadIdx.x;                    \
  const int w = tid >> 6, lane = tid & 63;        \
  const int fr = lane & 15, fk = (lane >> 4) * 8; \
  const int mw = (w >> 1) * 64, nw = (w & 1) * 64;\
  const int cr = (lane >> 4) * 4, cc = lane & 15;

// ---- S2: [proj | Gb] = F @ [W1;W2b]^T + [b1;b2] ------------------------------
__global__ __launch_bounds__(256) void pg_mfma(
    const bf16_t* __restrict__ Fbf, const bf16_t* __restrict__ Wpg,
    const float* __restrict__ b1, const float* __restrict__ b2,
    bf16_t* __restrict__ projbf, bf16_t* __restrict__ Gbbf) {
  __shared__ bf16_t As[128 * 32], Bs[128 * 32];
  TILE_IDS
  const int m0 = blockIdx.y * 128, n0 = blockIdx.x * 128;
  f32x4 acc[4][4] = {};
  GEMM_CORE(Fbf + (size_t)m0 * DIM, DIM, Wpg + (size_t)n0 * DIM, DIM, DIM, As, Bs, acc);
  const bool isProj = (n0 < 512);
  bf16_t* dst = isProj ? projbf : Gbbf;
  const float* bias = isProj ? b1 : b2;
  const int nb = isProj ? n0 : n0 - 512;
#pragma unroll
  for (int s = 0; s < 4; ++s)
#pragma unroll
    for (int t = 0; t < 4; ++t) {
      const int col = nb + nw + t * 16 + cc;
      const float bv = bias[col];
#pragma unroll
      for (int r = 0; r < 4; ++r)
        dst[(size_t)(m0 + mw + s * 16 + cr + r) * HID + col] = (bf16_t)(acc[s][t][r] + bv);
    }
}

// ---- S3: weight[b] = proj[b] @ F[b]^T ----------------------------------------
__global__ __launch_bounds__(256) void weight_mfma(
    const bf16_t* __restrict__ projbf, const bf16_t* __restrict__ Fbf,
    bf16_t* __restrict__ wbuf, int b0) {
  __shared__ bf16_t As[128 * 32], Bs[128 * 32];
  TILE_IDS
  const int b = b0 + blockIdx.z;
  const bf16_t* A  = projbf + (size_t)b * SEQ * DIM;
  const bf16_t* Bt = Fbf    + (size_t)b * SEQ * DIM;
  bf16_t* C = wbuf + (size_t)blockIdx.z * SEQ * SEQ;
  const int m0 = blockIdx.y * 128, n0 = blockIdx.x * 128;
  f32x4 acc[4][4] = {};
  GEMM_CORE(A + (size_t)m0 * DIM, DIM, Bt + (size_t)n0 * DIM, DIM, DIM, As, Bs, acc);
#pragma unroll
  for (int s = 0; s < 4; ++s)
#pragma unroll
    for (int t = 0; t < 4; ++t)
#pragma unroll
      for (int r = 0; r < 4; ++r)
        C[(size_t)(m0 + mw + s * 16 + cr + r) * SEQ + n0 + nw + t * 16 + cc] = (bf16_t)acc[s][t][r];
}

// ---- S4: GacT[b][m][j] = ([W2a;W2c] @ F[b]^T)[m][j] * sm_j -------------------
__global__ __launch_bounds__(256) void gact_mfma(
    const bf16_t* __restrict__ W2ac, const bf16_t* __restrict__ Fbf,
    const int* __restrict__ smask, bf16_t* __restrict__ GacT) {
  __shared__ bf16_t As[128 * 32], Bs[128 * 32];
  TILE_IDS
  const int b = blockIdx.z;
  const bf16_t* Bt = Fbf + (size_t)b * SEQ * DIM;
  const int m0 = blockIdx.y * 128, n0 = blockIdx.x * 128;
  f32x4 acc[4][4] = {};
  GEMM_CORE(W2ac + (size_t)m0 * DIM, DIM, Bt + (size_t)n0 * DIM, DIM, DIM, As, Bs, acc);
  bf16_t* C = GacT + (size_t)b * SEQ * SEQ;
#pragma unroll
  for (int s = 0; s < 4; ++s)
#pragma unroll
    for (int t = 0; t < 4; ++t) {
      const int j = n0 + nw + t * 16 + cc;
      const float smj = (float)smask[b * SEQ + j];
#pragma unroll
      for (int r = 0; r < 4; ++r)
        C[(size_t)(m0 + mw + s * 16 + cr + r) * SEQ + j] = (bf16_t)(acc[s][t][r] * smj);
    }
}

// ---- S5: tri — out = sp*(trilW @ GaT^T) + sf*(triuW @ GcT^T) + Gb ------------
// block tile 128(i) x 64(n); waves: mw=(w>>1)*64, nw2=(w&1)*32; frags 4(s) x 2(t).
__global__ __launch_bounds__(256) void tri_mfma(
    const bf16_t* __restrict__ wbuf, const bf16_t* __restrict__ GacT,
    const bf16_t* __restrict__ Gbbf,
    const float* __restrict__ scaleP, const float* __restrict__ scaleF,
    float* __restrict__ out, int b0) {
  __shared__ bf16_t As[128 * 32], BPs[64 * 32], BFs[64 * 32];
  const int tid = threadIdx.x;
  const int w = tid >> 6, lane = tid & 63;
  const int fr = lane & 15, fk = (lane >> 4) * 8;
  const int mw = (w >> 1) * 64, nw2 = (w & 1) * 32;
  const int cr = (lane >> 4) * 4, cc = lane & 15;
  const int b = b0 + blockIdx.z;
  const bf16_t* A   = wbuf + (size_t)blockIdx.z * SEQ * SEQ;
  const bf16_t* GaT = GacT + (size_t)b * SEQ * SEQ;            // rows 0..511: a, 512..1023: c
  const int i0 = blockIdx.y * 128, n0 = blockIdx.x * 64;
  f32x4 accP[4][2] = {}, accF[4][2] = {};
  for (int j0 = 0; j0 < SEQ; j0 += 32) {
    const bool blkP = (j0 < i0 + 128);        // block has any j<i
    const bool blkF = (j0 + 31 > i0);         // block has any j>i
    __syncthreads();
    stage<128>(A + (size_t)i0 * SEQ + j0, SEQ, As, w, lane);
    if (blkP) stage<64>(GaT + (size_t)n0 * SEQ + j0, SEQ, BPs, w, lane);
    if (blkF) stage<64>(GaT + (size_t)(512 + n0) * SEQ + j0, SEQ, BFs, w, lane);
    __syncthreads();
    const bool wP = (j0 < i0 + mw + 64);      // wave has any past work
    const bool wF = (j0 + 31 > i0 + mw);      // wave has any future work
    if (!wP && !wF) continue;
    bf16x8 bP[2], bF[2];
#pragma unroll
    for (int t = 0; t < 2; ++t) {
      if (wP) bP[t] = *(const bf16x8*)&BPs[(nw2 + t * 16 + fr) * 32 + fk];
      if (wF) bF[t] = *(const bf16x8*)&BFs[(nw2 + t * 16 + fr) * 32 + fk];
    }
#pragma unroll
    for (int s = 0; s < 4; ++s) {
      const int rlo = i0 + mw + s * 16;
      const bool pAny = (j0 < rlo + 15), pFull = (j0 + 31 < rlo);
      const bool fAny = (j0 + 31 > rlo), fFull = (j0 > rlo + 15);
      if (!pAny && !fAny) continue;
      const bf16x8 a = *(const bf16x8*)&As[(mw + s * 16 + fr) * 32 + fk];
      if (pFull) {
#pragma unroll
        for (int t = 0; t < 2; ++t)
          accP[s][t] = __builtin_amdgcn_mfma_f32_16x16x32_bf16(a, bP[t], accP[s][t], 0, 0, 0);
      } else if (pAny) {
        const int cut = (rlo + fr) - (j0 + fk);     // keep e < cut  (j < i)
        bf16x8 ap = a;
#pragma unroll
        for (int e = 0; e < 8; ++e) if (e >= cut) ap[e] = (bf16_t)0.f;
#pragma unroll
        for (int t = 0; t < 2; ++t)
          accP[s][t] = __builtin_amdgcn_mfma_f32_16x16x32_bf16(ap, bP[t], accP[s][t], 0, 0, 0);
      }
      if (fFull) {
#pragma unroll
        for (int t = 0; t < 2; ++t)
          accF[s][t] = __builtin_amdgcn_mfma_f32_16x16x32_bf16(a, bF[t], accF[s][t], 0, 0, 0);
      } else if (fAny) {
        const int cut = (rlo + fr) - (j0 + fk);     // keep e > cut  (j > i)
        bf16x8 af = a;
#pragma unroll
        for (int e = 0; e < 8; ++e) if (e <= cut) af[e] = (bf16_t)0.f;
#pragma unroll
        for (int t = 0; t < 2; ++t)
          accF[s][t] = __builtin_amdgcn_mfma_f32_16x16x32_bf16(af, bF[t], accF[s][t], 0, 0, 0);
      }
    }
  }
#pragma unroll
  for (int s = 0; s < 4; ++s)
#pragma unroll
    for (int r = 0; r < 4; ++r) {
      const int row = i0 + mw + s * 16 + cr + r;
      const float spv = scaleP[b * SEQ + row];
      const float sfv = scaleF[b * SEQ + row];
#pragma unroll
      for (int t = 0; t < 2; ++t) {
        const int col = n0 + nw2 + t * 16 + cc;
        const size_t oi = ((size_t)b * SEQ + row) * HID + col;
        out[oi] = accP[s][t][r] * spv + accF[s][t][r] * sfv + (float)Gbbf[oi];
      }
    }
}

extern "C" void kernel_launch(void* const* d_in, const int* in_sizes, int n_in,
                              void* d_out, int out_size, void* d_ws, size_t ws_size,
                              hipStream_t stream) {
  const float* F  = (const float*)d_in[0];
  const int*   sm = (const int*)  d_in[1];
  const float* W1 = (const float*)d_in[2];
  const float* b1 = (const float*)d_in[3];
  const float* W2 = (const float*)d_in[4];
  const float* b2 = (const float*)d_in[5];
  float* out = (float*)d_out;

  char* ws = (char*)d_ws;
  size_t off = 0;
  auto take = [&](size_t bytes) -> void* {
    void* p = ws + off;
    off += (bytes + 255) & ~(size_t)255;
    return p;
  };
  bf16_t* Fbf    = (bf16_t*)take((size_t)BATCH * SEQ * DIM * 2);   // 8 MB
  bf16_t* projbf = (bf16_t*)take((size_t)BATCH * SEQ * HID * 2);   // 8 MB
  bf16_t* GacT   = (bf16_t*)take((size_t)BATCH * SEQ * SEQ * 2);   // 16 MB
  bf16_t* Gbbf   = (bf16_t*)take((size_t)BATCH * SEQ * HID * 2);   // 8 MB
  bf16_t* Wpg    = (bf16_t*)take((size_t)1024 * 512 * 2);          // 1 MB
  bf16_t* W2ac   = (bf16_t*)take((size_t)1024 * 512 * 2);          // 1 MB
  float*  scaleP = (float*) take((size_t)BATCH * SEQ * 4);
  float*  scaleF = (float*) take((size_t)BATCH * SEQ * 4);

  const size_t wbytes = (size_t)SEQ * SEQ * 2;
  int chunk = (ws_size > off) ? (int)((ws_size - off) / wbytes) : 1;
  if (chunk > BATCH) chunk = BATCH;
  if (chunk < 1) chunk = 1;
  bf16_t* wbuf = (bf16_t*)(ws + off);

  scales_kernel<<<dim3(BATCH), dim3(1024), 0, stream>>>(sm, scaleP, scaleF);
  cvt_kernel<<<dim3(BATCH * SEQ * DIM / 8 / 256), dim3(256), 0, stream>>>(F, Fbf, BATCH * SEQ * DIM / 8);
  prepw_kernel<<<dim3(512), dim3(256), 0, stream>>>(W1, W2, Wpg, W2ac);

  pg_mfma<<<dim3(1024 / 128, BATCH * SEQ / 128), dim3(256), 0, stream>>>(
      Fbf, Wpg, b1, b2, projbf, Gbbf);
  gact_mfma<<<dim3(SEQ / 128, SEQ / 128, BATCH), dim3(256), 0, stream>>>(
      W2ac, Fbf, sm, GacT);
  for (int b0 = 0; b0 < BATCH; b0 += chunk) {
    const int nb = (BATCH - b0 < chunk) ? (BATCH - b0) : chunk;
    weight_mfma<<<dim3(SEQ / 128, SEQ / 128, nb), dim3(256), 0, stream>>>(projbf, Fbf, wbuf, b0);
    tri_mfma<<<dim3(HID / 64, SEQ / 128, nb), dim3(256), 0, stream>>>(
        wbuf, GacT, Gbbf, scaleP, scaleF, out, b0);
  }
}